// Round 2
// baseline (24.146 us; speedup 1.0000x reference)
//
#include <hip/hip_runtime.h>

// QNN_Q3: 3-qubit StronglyEntanglingLayers, B=128, T=64, D=96, 3 chained
// layers, nb=32, vqc_depth=2.
// Round 1: precompute the 36,864 Rot matrices (shared across B=128) into
// d_ws as (X,Y,U,V) float4s; main kernel does only 3 embedding sincos per
// circuit and reads rots as lane-coalesced float4 loads.

struct cpx { float re, im; };

// ======================= precompute kernel =======================
// theta: (T=64, 3, 32, 2, 3, 3) f32
// rot table layout: [tl = t*3+l][j = vl*3+q][i = block 0..31] -> float4(X,Y,U,V)
//   U00 = ( X,  Y), U01 = (-U, -V), U10 = ( U, -V), U11 = ( X, -Y)
#define N_ROTS (64 * 3 * 6 * 32)   // 36864

__global__ __launch_bounds__(256) void qnn_rot_pre(const float* __restrict__ theta,
                                                   float4* __restrict__ rot) {
    int gid = blockIdx.x * 256 + threadIdx.x;
    if (gid >= N_ROTS) return;
    int i  = gid & 31;
    int j  = (gid >> 5) % 6;       // vl*3 + q
    int tl = gid / (6 * 32);       // t*3 + l
    int vl = j / 3, q = j % 3;
    const float* p = theta + ((((size_t)tl * 32 + i) * 2 + vl) * 3 + q) * 3;
    float phi = p[0], tht = p[1], omg = p[2];
    float st, ct; __sincosf(0.5f * tht, &st, &ct);
    float sa, ca; __sincosf(-0.5f * (phi + omg), &sa, &ca);  // a = ca + i*sa
    float sb, cb; __sincosf(0.5f * (phi - omg), &sb, &cb);   // b = cb + i*sb
    rot[gid] = make_float4(ca * ct, sa * ct, cb * st, sb * st);
}

// ======================= main kernel =======================

__device__ __forceinline__ void rot_apply_pre(cpx psi[8], float4 r, int bit) {
    const float X = r.x, Y = r.y, U = r.z, V = r.w;
#pragma unroll
    for (int i = 0; i < 8; ++i) {
        if (i & bit) continue;
        cpx p0 = psi[i], p1 = psi[i | bit];
        cpx o0, o1;
        o0.re = X * p0.re - Y * p0.im - U * p1.re + V * p1.im;
        o0.im = X * p0.im + Y * p0.re - U * p1.im - V * p1.re;
        o1.re = U * p0.re + V * p0.im + X * p1.re + Y * p1.im;
        o1.im = U * p0.im - V * p0.re + X * p1.im - Y * p1.re;
        psi[i] = o0; psi[i | bit] = o1;
    }
}

__device__ __forceinline__ void cnot(cpx psi[8], int cb, int tb) {
#pragma unroll
    for (int i = 0; i < 8; ++i) {
        if ((i & cb) && !(i & tb)) {
            cpx tmp = psi[i]; psi[i] = psi[i | tb]; psi[i | tb] = tmp;
        }
    }
}

__device__ __forceinline__ void circuit_pre(const float ang[3], const float4 r[6],
                                            float out[3]) {
    float c[3], s[3];
#pragma unroll
    for (int q = 0; q < 3; ++q) __sincosf(0.5f * ang[q], &s[q], &c[q]);
    cpx psi[8];
#pragma unroll
    for (int i = 0; i < 8; ++i) {
        float v = ((i & 4) ? s[0] : c[0]) * ((i & 2) ? s[1] : c[1]) * ((i & 1) ? s[2] : c[2]);
        psi[i].re = v; psi[i].im = 0.0f;   // compiler folds im=0 through layer-0 rots
    }
#pragma unroll
    for (int vl = 0; vl < 2; ++vl) {
#pragma unroll
        for (int q = 0; q < 3; ++q) rot_apply_pre(psi, r[vl * 3 + q], 4 >> q);
        int rr = vl + 1;
#pragma unroll
        for (int q = 0; q < 3; ++q) cnot(psi, 4 >> q, 4 >> ((q + rr) % 3));
    }
    float p[8];
#pragma unroll
    for (int i = 0; i < 8; ++i) p[i] = psi[i].re * psi[i].re + psi[i].im * psi[i].im;
    out[0] = (p[0] + p[1] + p[2] + p[3]) - (p[4] + p[5] + p[6] + p[7]);
    out[1] = (p[0] + p[1] + p[4] + p[5]) - (p[2] + p[3] + p[6] + p[7]);
    out[2] = (p[0] + p[2] + p[4] + p[6]) - (p[1] + p[3] + p[5] + p[7]);
}

#define PAIRS_PER_BLOCK 8

__global__ __launch_bounds__(256) void qnn_q3_main(const float* __restrict__ x,
                                                   const float4* __restrict__ rot,
                                                   float* __restrict__ out) {
    const int T = 64, D = 96;
    __shared__ float H[PAIRS_PER_BLOCK][96];

    const int pair = threadIdx.x >> 5;
    const int i = threadIdx.x & 31;
    const int bt = blockIdx.x * PAIRS_PER_BLOCK + pair;
    const int t = bt % T;

    float res[3];
    float ang[3];
    // ---- layer 0: contiguous 3-wide blocks of x ----
    {
        const float* xp = x + (size_t)bt * D;
        ang[0] = xp[3 * i]; ang[1] = xp[3 * i + 1]; ang[2] = xp[3 * i + 2];
        const float4* rt = rot + ((size_t)t * 3 + 0) * 6 * 32 + i;
        float4 r[6];
#pragma unroll
        for (int j = 0; j < 6; ++j) r[j] = rt[j * 32];   // lane-coalesced
        circuit_pre(ang, r, res);
    }
    H[pair][3 * i] = res[0]; H[pair][3 * i + 1] = res[1]; H[pair][3 * i + 2] = res[2];
    __syncthreads();

    // ---- layers 1..2: rewired reads [3i-1, 3i+1, 3i+3] mod 96 ----
#pragma unroll
    for (int l = 1; l < 3; ++l) {
        const int j0 = (3 * i + 95) % 96;
        const int j1 = (3 * i + 1) % 96;
        const int j2 = (3 * i + 3) % 96;
        ang[0] = H[pair][j0]; ang[1] = H[pair][j1]; ang[2] = H[pair][j2];
        __syncthreads();
        const float4* rt = rot + ((size_t)t * 3 + l) * 6 * 32 + i;
        float4 r[6];
#pragma unroll
        for (int j = 0; j < 6; ++j) r[j] = rt[j * 32];
        circuit_pre(ang, r, res);
        if (l == 2) {
            float* op = out + (size_t)bt * D;
            op[3 * i] = res[0]; op[3 * i + 1] = res[1]; op[3 * i + 2] = res[2];
        } else {
            H[pair][3 * i] = res[0]; H[pair][3 * i + 1] = res[1]; H[pair][3 * i + 2] = res[2];
            __syncthreads();
        }
    }
}

// ======================= fallback (round-0 self-contained) =======================

__device__ __forceinline__ cpx cmul(cpx a, cpx b) {
    cpx r; r.re = a.re * b.re - a.im * b.im; r.im = a.re * b.im + a.im * b.re; return r;
}

__device__ __forceinline__ void rot_apply(cpx psi[8], float phi, float tht, float omg, int bit) {
    float st, ct; __sincosf(0.5f * tht, &st, &ct);
    float sa, ca; __sincosf(-0.5f * (phi + omg), &sa, &ca);
    float sb, cb; __sincosf(0.5f * (phi - omg), &sb, &cb);
    float4 r = make_float4(ca * ct, sa * ct, cb * st, sb * st);
    rot_apply_pre(psi, r, bit);
}

__device__ __forceinline__ void circuit(const float ang[3], const float* __restrict__ th,
                                        float out[3]) {
    float c[3], s[3];
#pragma unroll
    for (int q = 0; q < 3; ++q) __sincosf(0.5f * ang[q], &s[q], &c[q]);
    cpx psi[8];
#pragma unroll
    for (int i = 0; i < 8; ++i) {
        float v = ((i & 4) ? s[0] : c[0]) * ((i & 2) ? s[1] : c[1]) * ((i & 1) ? s[2] : c[2]);
        psi[i].re = v; psi[i].im = 0.0f;
    }
#pragma unroll
    for (int vl = 0; vl < 2; ++vl) {
#pragma unroll
        for (int q = 0; q < 3; ++q) {
            const float* p = th + (vl * 3 + q) * 3;
            rot_apply(psi, p[0], p[1], p[2], 4 >> q);
        }
        int rr = vl + 1;
#pragma unroll
        for (int q = 0; q < 3; ++q) cnot(psi, 4 >> q, 4 >> ((q + rr) % 3));
    }
    float p[8];
#pragma unroll
    for (int i = 0; i < 8; ++i) p[i] = psi[i].re * psi[i].re + psi[i].im * psi[i].im;
    out[0] = (p[0] + p[1] + p[2] + p[3]) - (p[4] + p[5] + p[6] + p[7]);
    out[1] = (p[0] + p[1] + p[4] + p[5]) - (p[2] + p[3] + p[6] + p[7]);
    out[2] = (p[0] + p[2] + p[4] + p[6]) - (p[1] + p[3] + p[5] + p[7]);
}

__global__ __launch_bounds__(256) void qnn_q3_fallback(const float* __restrict__ x,
                                                       const float* __restrict__ theta,
                                                       float* __restrict__ out) {
    const int T = 64, D = 96;
    __shared__ float H[PAIRS_PER_BLOCK][96];
    const int pair = threadIdx.x >> 5;
    const int i = threadIdx.x & 31;
    const int bt = blockIdx.x * PAIRS_PER_BLOCK + pair;
    const int t = bt % T;

    const float* xp = x + (size_t)bt * D;
    float ang[3] = { xp[3 * i], xp[3 * i + 1], xp[3 * i + 2] };
    float res[3];
    circuit(ang, theta + (((size_t)t * 3 + 0) * 32 + i) * 18, res);
    H[pair][3 * i] = res[0]; H[pair][3 * i + 1] = res[1]; H[pair][3 * i + 2] = res[2];
    __syncthreads();
#pragma unroll
    for (int l = 1; l < 3; ++l) {
        const int j0 = (3 * i + 95) % 96;
        const int j1 = (3 * i + 1) % 96;
        const int j2 = (3 * i + 3) % 96;
        ang[0] = H[pair][j0]; ang[1] = H[pair][j1]; ang[2] = H[pair][j2];
        __syncthreads();
        circuit(ang, theta + (((size_t)t * 3 + l) * 32 + i) * 18, res);
        if (l == 2) {
            float* op = out + (size_t)bt * D;
            op[3 * i] = res[0]; op[3 * i + 1] = res[1]; op[3 * i + 2] = res[2];
        } else {
            H[pair][3 * i] = res[0]; H[pair][3 * i + 1] = res[1]; H[pair][3 * i + 2] = res[2];
            __syncthreads();
        }
    }
}

extern "C" void kernel_launch(void* const* d_in, const int* in_sizes, int n_in,
                              void* d_out, int out_size, void* d_ws, size_t ws_size,
                              hipStream_t stream) {
    const float* x = (const float*)d_in[0];       // (128, 64, 96) f32
    const float* theta = (const float*)d_in[1];   // (64, 3, 32, 2, 3, 3) f32
    float* out = (float*)d_out;                   // (128, 64, 96) f32

    const int BT = 128 * 64;
    const int blocks = BT / PAIRS_PER_BLOCK;      // 1024

    if (ws_size >= (size_t)N_ROTS * sizeof(float4)) {
        float4* rot = (float4*)d_ws;
        qnn_rot_pre<<<(N_ROTS + 255) / 256, 256, 0, stream>>>(theta, rot);
        qnn_q3_main<<<blocks, 256, 0, stream>>>(x, rot, out);
    } else {
        qnn_q3_fallback<<<blocks, 256, 0, stream>>>(x, theta, out);
    }
}

// Round 3
// 18.721 us; speedup vs baseline: 1.2898x; 1.2898x over previous
//
#include <hip/hip_runtime.h>

// QNN_Q3: 3-qubit StronglyEntanglingLayers, B=128, T=64, D=96, 3 chained
// layers, nb=32 blocks/pair, vqc_depth=2.
// Round 2: single fused kernel. Blocks group 8 (b,t) pairs sharing one t:
//  - stage theta[t] to LDS (coalesced), compute all 576 rot matrices in-block
//  - one thread = one circuit; inter-layer rewiring via __shfl within the
//    32-thread pair group (no LDS H, no inter-layer barriers)
//  - __launch_bounds__(256,6) for ~6 waves/SIMD.

#define T_DIM 64
#define D_DIM 96
#define NB 32
#define NLAYER 3
#define ROTS_PER_T (NLAYER * 6 * NB)            // 576
#define THETA_PER_T (NLAYER * NB * 2 * 3 * 3)   // 1728 floats

struct cpx { float re, im; };

// U00=( X, Y), U01=(-U,-V), U10=( U,-V), U11=( X,-Y); r=(X,Y,U,V)
__device__ __forceinline__ void rot_apply_pre(cpx psi[8], float4 r, int bit) {
    const float X = r.x, Y = r.y, U = r.z, V = r.w;
#pragma unroll
    for (int k = 0; k < 8; ++k) {
        if (k & bit) continue;
        cpx p0 = psi[k], p1 = psi[k | bit];
        cpx o0, o1;
        o0.re = X * p0.re - Y * p0.im - U * p1.re + V * p1.im;
        o0.im = X * p0.im + Y * p0.re - U * p1.im - V * p1.re;
        o1.re = U * p0.re + V * p0.im + X * p1.re + Y * p1.im;
        o1.im = U * p0.im - V * p0.re + X * p1.im - Y * p1.re;
        psi[k] = o0; psi[k | bit] = o1;
    }
}

__device__ __forceinline__ void cnot(cpx psi[8], int cb, int tb) {
#pragma unroll
    for (int k = 0; k < 8; ++k) {
        if ((k & cb) && !(k & tb)) {
            cpx tmp = psi[k]; psi[k] = psi[k | tb]; psi[k | tb] = tmp;
        }
    }
}

__global__ __launch_bounds__(256, 6) void qnn_fused(const float* __restrict__ x,
                                                    const float* __restrict__ theta,
                                                    float* __restrict__ out) {
    __shared__ float  thetaS[THETA_PER_T];   // 6912 B
    __shared__ float4 rotS[ROTS_PER_T];      // 9216 B

    const int tid = threadIdx.x;
    const int t  = blockIdx.x >> 4;          // 64 t values
    const int bg = blockIdx.x & 15;          // 16 groups of 8 b each

    // ---- stage theta[t] (coalesced) ----
    const float* gth = theta + (size_t)t * THETA_PER_T;
#pragma unroll
    for (int k = tid; k < THETA_PER_T; k += 256) thetaS[k] = gth[k];
    __syncthreads();

    // ---- compute 576 rot matrices for this t ----
    for (int idx = tid; idx < ROTS_PER_T; idx += 256) {
        int l   = idx / 192;
        int rem = idx - l * 192;
        int j   = rem >> 5;                  // vl*3+q
        int i   = rem & 31;                  // circuit block
        const float* p = &thetaS[((l * NB + i) * 6 + j) * 3];
        float phi = p[0], tht = p[1], omg = p[2];
        float st, ct; __sincosf(0.5f * tht, &st, &ct);
        float sa, ca; __sincosf(-0.5f * (phi + omg), &sa, &ca);  // a = ca+i*sa
        float sb, cb; __sincosf(0.5f * (phi - omg), &sb, &cb);   // b = cb+i*sb
        rotS[idx] = make_float4(ca * ct, sa * ct, cb * st, sb * st);
    }
    __syncthreads();

    // ---- 8 pairs per block, one circuit per thread ----
    const int pr = tid >> 5;                 // pair slot 0..7
    const int i  = tid & 31;                 // circuit index in pair
    const int b  = bg * 8 + pr;
    const int bt = b * T_DIM + t;

    const float* xp = x + (size_t)bt * D_DIM + 3 * i;
    float ang0 = xp[0], ang1 = xp[1], ang2 = xp[2];

    float res0 = 0.f, res1 = 0.f, res2 = 0.f;
#pragma unroll
    for (int l = 0; l < NLAYER; ++l) {
        if (l) {
            // rewiring [3i-1, 3i+1, 3i+3] mod 96 within the 32-thread group
            ang0 = __shfl(res2, (i + 31) & 31, 32);
            ang1 = res1;
            ang2 = __shfl(res0, (i + 1) & 31, 32);
        }
        float c0, s0, c1, s1, c2, s2;
        __sincosf(0.5f * ang0, &s0, &c0);
        __sincosf(0.5f * ang1, &s1, &c1);
        __sincosf(0.5f * ang2, &s2, &c2);
        cpx psi[8];
        {
            float cc = c0 * c1, cs = c0 * s1, sc = s0 * c1, ss = s0 * s1;
            psi[0].re = cc * c2; psi[1].re = cc * s2;
            psi[2].re = cs * c2; psi[3].re = cs * s2;
            psi[4].re = sc * c2; psi[5].re = sc * s2;
            psi[6].re = ss * c2; psi[7].re = ss * s2;
#pragma unroll
            for (int k = 0; k < 8; ++k) psi[k].im = 0.0f;
        }
        const float4* rl = &rotS[l * 192 + i];
#pragma unroll
        for (int vl = 0; vl < 2; ++vl) {
#pragma unroll
            for (int q = 0; q < 3; ++q) rot_apply_pre(psi, rl[(vl * 3 + q) * 32], 4 >> q);
            int rr = vl + 1;                 // CNOT range: (vl % 2) + 1
#pragma unroll
            for (int q = 0; q < 3; ++q) cnot(psi, 4 >> q, 4 >> ((q + rr) % 3));
        }
        float pb[8];
#pragma unroll
        for (int k = 0; k < 8; ++k)
            pb[k] = psi[k].re * psi[k].re + psi[k].im * psi[k].im;
        res0 = (pb[0] + pb[1] + pb[2] + pb[3]) - (pb[4] + pb[5] + pb[6] + pb[7]);
        res1 = (pb[0] + pb[1] + pb[4] + pb[5]) - (pb[2] + pb[3] + pb[6] + pb[7]);
        res2 = (pb[0] + pb[2] + pb[4] + pb[6]) - (pb[1] + pb[3] + pb[5] + pb[7]);
    }

    float* op = out + (size_t)bt * D_DIM + 3 * i;
    op[0] = res0; op[1] = res1; op[2] = res2;
}

extern "C" void kernel_launch(void* const* d_in, const int* in_sizes, int n_in,
                              void* d_out, int out_size, void* d_ws, size_t ws_size,
                              hipStream_t stream) {
    const float* x = (const float*)d_in[0];       // (128, 64, 96) f32
    const float* theta = (const float*)d_in[1];   // (64, 3, 32, 2, 3, 3) f32
    float* out = (float*)d_out;                   // (128, 64, 96) f32

    // grid: 64 t-values x 16 b-groups (8 b each) = 1024 blocks
    qnn_fused<<<64 * 16, 256, 0, stream>>>(x, theta, out);
}

// Round 4
// 13.530 us; speedup vs baseline: 1.7846x; 1.3837x over previous
//
#include <hip/hip_runtime.h>

// QNN_Q3: 3-qubit StronglyEntanglingLayers, B=128, T=64, D=96, 3 chained
// layers, nb=32, vqc_depth=2. One thread = one circuit; 8 (b,t) pairs per
// 256-thread block, all sharing one t; rot matrices (t-shared across B)
// computed once per block into LDS.
// Round 3: packed-f32 complex butterflies (v_pk_fma_f32 via float2
// ext-vectors), launch_bounds(256,4) (grid-limited occupancy anyway, give
// the scheduler 128 VGPRs), explicit rr[6] rot prefetch per layer, early x
// loads, theta read directly from global (no LDS staging barrier).

#define T_DIM 64
#define D_DIM 96
#define NB 32
#define NLAYER 3
#define ROTS_PER_T (NLAYER * 6 * NB)            // 576
#define THETA_PER_T (NLAYER * NB * 18)          // 1728 floats

typedef float v2f __attribute__((ext_vector_type(2)));

// Rot matrix from r=(X,Y,U,V): U00=(X,Y), U01=(-U,-V), U10=(U,-V), U11=(X,-Y)
// o0 = U00*p0 + U01*p1 ; o1 = U10*p0 + U11*p1   (complex, (re,im) packed)
// o0 = Xb*p0 + Yn*swap(p0) - Ub*p1 + Vn*swap(p1)
// o1 = Ub*p0 + Vn*swap(p0) + Xb*p1 - Yn*swap(p1)
// with Xb=(X,X), Yn=(-Y,Y), Ub=(U,U), Vn=(V,-V).
__device__ __forceinline__ void rot_pk(v2f psi[8], float4 r, int bit) {
    const v2f Xb = {r.x, r.x};
    const v2f Yn = {-r.y, r.y};
    const v2f Ub = {r.z, r.z};
    const v2f Vn = {r.w, -r.w};
#pragma unroll
    for (int k = 0; k < 8; ++k) {
        if (k & bit) continue;
        v2f p0 = psi[k], p1 = psi[k | bit];
        v2f s0 = {p0.y, p0.x}, s1 = {p1.y, p1.x};
        v2f o0 = Xb * p0 + Yn * s0 - Ub * p1 + Vn * s1;
        v2f o1 = Ub * p0 + Vn * s0 + Xb * p1 - Yn * s1;
        psi[k] = o0; psi[k | bit] = o1;
    }
}

__device__ __forceinline__ void cnot(v2f psi[8], int cb, int tb) {
#pragma unroll
    for (int k = 0; k < 8; ++k) {
        if ((k & cb) && !(k & tb)) {
            v2f tmp = psi[k]; psi[k] = psi[k | tb]; psi[k | tb] = tmp;
        }
    }
}

__global__ __launch_bounds__(256, 4) void qnn_fused(const float* __restrict__ x,
                                                    const float* __restrict__ theta,
                                                    float* __restrict__ out) {
    __shared__ float4 rotS[ROTS_PER_T];   // 9216 B

    const int tid = threadIdx.x;
    const int t  = blockIdx.x >> 4;       // 64 t values
    const int bg = blockIdx.x & 15;       // 16 groups of 8 b each
    const int pr = tid >> 5;              // pair slot 0..7
    const int i  = tid & 31;              // circuit index within (b,t)
    const int b  = bg * 8 + pr;
    const int bt = b * T_DIM + t;

    // ---- early x loads (latency hides under rot-table construction) ----
    const float* xp = x + (size_t)bt * D_DIM + 3 * i;
    const float a0 = xp[0], a1 = xp[1], a2 = xp[2];

    // ---- build rot table for this t (576 entries, theta direct from L2) ----
    const float* gth = theta + (size_t)t * THETA_PER_T;
    for (int idx = tid; idx < ROTS_PER_T; idx += 256) {
        int l   = idx / 192;
        int rem = idx - l * 192;
        int j   = rem >> 5;               // vl*3+q
        int ii  = rem & 31;               // circuit block
        const float* p = gth + ((l * NB + ii) * 6 + j) * 3;
        float phi = p[0], tht = p[1], omg = p[2];
        float st, ct; __sincosf(0.5f * tht, &st, &ct);
        float sa, ca; __sincosf(-0.5f * (phi + omg), &sa, &ca);  // a = ca+i*sa
        float sb, cb; __sincosf(0.5f * (phi - omg), &sb, &cb);   // b = cb+i*sb
        rotS[idx] = make_float4(ca * ct, sa * ct, cb * st, sb * st);
    }
    __syncthreads();

    // ---- 3 chained layers, one circuit per thread per layer ----
    float ang0 = a0, ang1 = a1, ang2 = a2;
    float res0 = 0.f, res1 = 0.f, res2 = 0.f;
#pragma unroll
    for (int l = 0; l < NLAYER; ++l) {
        if (l) {
            // rewiring [3i-1, 3i+1, 3i+3] mod 96 within the 32-thread group
            ang0 = __shfl(res2, (i + 31) & 31, 32);
            ang1 = res1;
            ang2 = __shfl(res0, (i + 1) & 31, 32);
        }
        // prefetch this layer's 6 rot matrices into registers (batched ds_read)
        float4 rr[6];
#pragma unroll
        for (int j = 0; j < 6; ++j) rr[j] = rotS[l * 192 + j * 32 + i];

        float c0, s0, c1, s1, c2, s2;
        __sincosf(0.5f * ang0, &s0, &c0);
        __sincosf(0.5f * ang1, &s1, &c1);
        __sincosf(0.5f * ang2, &s2, &c2);
        v2f psi[8];
        {
            float cc = c0 * c1, cs = c0 * s1, sc = s0 * c1, ss = s0 * s1;
            psi[0] = (v2f){cc * c2, 0.f}; psi[1] = (v2f){cc * s2, 0.f};
            psi[2] = (v2f){cs * c2, 0.f}; psi[3] = (v2f){cs * s2, 0.f};
            psi[4] = (v2f){sc * c2, 0.f}; psi[5] = (v2f){sc * s2, 0.f};
            psi[6] = (v2f){ss * c2, 0.f}; psi[7] = (v2f){ss * s2, 0.f};
        }
#pragma unroll
        for (int vl = 0; vl < 2; ++vl) {
#pragma unroll
            for (int q = 0; q < 3; ++q) rot_pk(psi, rr[vl * 3 + q], 4 >> q);
            int rngr = vl + 1;            // CNOT range: (vl % 2) + 1
#pragma unroll
            for (int q = 0; q < 3; ++q) cnot(psi, 4 >> q, 4 >> ((q + rngr) % 3));
        }
        float pb[8];
#pragma unroll
        for (int k = 0; k < 8; ++k) {
            v2f sq = psi[k] * psi[k];
            pb[k] = sq.x + sq.y;
        }
        float s01 = pb[0] + pb[1], s23 = pb[2] + pb[3];
        float s45 = pb[4] + pb[5], s67 = pb[6] + pb[7];
        float q0 = pb[0] + pb[4], q1 = pb[1] + pb[5];
        float q2 = pb[2] + pb[6], q3 = pb[3] + pb[7];
        res0 = (s01 + s23) - (s45 + s67);
        res1 = (q0 + q1) - (q2 + q3);
        res2 = (q0 + q2) - (q1 + q3);
    }

    float* op = out + (size_t)bt * D_DIM + 3 * i;
    op[0] = res0; op[1] = res1; op[2] = res2;
}

extern "C" void kernel_launch(void* const* d_in, const int* in_sizes, int n_in,
                              void* d_out, int out_size, void* d_ws, size_t ws_size,
                              hipStream_t stream) {
    const float* x = (const float*)d_in[0];       // (128, 64, 96) f32
    const float* theta = (const float*)d_in[1];   // (64, 3, 32, 2, 3, 3) f32
    float* out = (float*)d_out;                   // (128, 64, 96) f32

    // grid: 64 t-values x 16 b-groups (8 b each) = 1024 blocks
    qnn_fused<<<64 * 16, 256, 0, stream>>>(x, theta, out);
}

// Round 5
// 11.464 us; speedup vs baseline: 2.1062x; 1.1802x over previous
//
#include <hip/hip_runtime.h>

// QNN_Q3: 3-qubit StronglyEntanglingLayers, B=128, T=64, D=96, 3 chained
// layers, nb=32, vqc_depth=2.
// Round 4: (a) 2 circuits (b, b+8) packed per thread as SoA v2f -> clean
// v_pk_fma_f32 complex math, no swizzles; (b) vl=0 Rots applied to 1-qubit
// factors of the product state + tensor expansion (~33% fewer gate ops);
// (c) grid 512 blocks (2/CU), prologue rot-table redundancy halved.

#define T_DIM 64
#define D_DIM 96
#define NB 32
#define NLAYER 3
#define ROTS_PER_T (NLAYER * 6 * NB)            // 576
#define THETA_PER_T (NLAYER * NB * 18)          // 1728 floats

typedef float v2f __attribute__((ext_vector_type(2)));

struct c2 { v2f re, im; };   // one amplitude, two packed circuits

__device__ __forceinline__ c2 cmul2(c2 a, c2 b) {
    c2 r;
    r.re = a.re * b.re - a.im * b.im;
    r.im = a.re * b.im + a.im * b.re;
    return r;
}

// Rot as 2x2 on a REAL 1-qubit state (c,s): U00=X+iY U01=-U-iV U10=U-iV U11=X-iY
__device__ __forceinline__ void apply1q(float4 r, v2f c, v2f s, c2& e0, c2& e1) {
    e0.re = r.x * c - r.z * s;          // X c - U s
    e0.im = r.y * c - r.w * s;          // Y c - V s
    e1.re = r.z * c + r.x * s;          // U c + X s
    e1.im = -(r.w * c + r.y * s);       // -(V c + Y s)
}

// Full complex butterfly on packed psi
__device__ __forceinline__ void gate_pk(c2 psi[8], float4 r, int bit) {
    const v2f X = {r.x, r.x}, Y = {r.y, r.y}, U = {r.z, r.z}, V = {r.w, r.w};
#pragma unroll
    for (int k = 0; k < 8; ++k) {
        if (k & bit) continue;
        c2 p0 = psi[k], p1 = psi[k | bit], o0, o1;
        o0.re = X * p0.re - Y * p0.im - U * p1.re + V * p1.im;
        o0.im = Y * p0.re + X * p0.im - V * p1.re - U * p1.im;
        o1.re = U * p0.re + V * p0.im + X * p1.re + Y * p1.im;
        o1.im = U * p0.im - V * p0.re + X * p1.im - Y * p1.re;
        psi[k] = o0; psi[k | bit] = o1;
    }
}

__device__ __forceinline__ void cnot_c2(c2 psi[8], int cb, int tb) {
#pragma unroll
    for (int k = 0; k < 8; ++k) {
        if ((k & cb) && !(k & tb)) {
            c2 tmp = psi[k]; psi[k] = psi[k | tb]; psi[k | tb] = tmp;
        }
    }
}

__device__ __forceinline__ void sc2(v2f a, v2f& s, v2f& c) {
    float sx, cx, sy, cy;
    __sincosf(0.5f * a.x, &sx, &cx);
    __sincosf(0.5f * a.y, &sy, &cy);
    s = (v2f){sx, sy}; c = (v2f){cx, cy};
}

__global__ __launch_bounds__(256, 2) void qnn_fused(const float* __restrict__ x,
                                                    const float* __restrict__ theta,
                                                    float* __restrict__ out) {
    __shared__ float4 rotS[ROTS_PER_T];   // 9216 B

    const int tid = threadIdx.x;
    const int t  = blockIdx.x >> 3;       // 64 t values
    const int bg = blockIdx.x & 7;        // 8 groups of 16 b
    const int pr = tid >> 5;              // 0..7
    const int i  = tid & 31;              // circuit index within (b,t)
    const int b0 = bg * 16 + pr;
    const int bt0 = b0 * T_DIM + t;
    const int bt1 = bt0 + 8 * T_DIM;      // b1 = b0 + 8

    // ---- early x loads (2 circuits) ----
    const float* xp0 = x + (size_t)bt0 * D_DIM + 3 * i;
    const float* xp1 = x + (size_t)bt1 * D_DIM + 3 * i;
    v2f ang0 = {xp0[0], xp1[0]};
    v2f ang1 = {xp0[1], xp1[1]};
    v2f ang2 = {xp0[2], xp1[2]};

    // ---- rot table for this t ----
    const float* gth = theta + (size_t)t * THETA_PER_T;
    for (int idx = tid; idx < ROTS_PER_T; idx += 256) {
        int l   = idx / 192;
        int rem = idx - l * 192;
        int j   = rem >> 5;               // vl*3+q
        int ii  = rem & 31;
        const float* p = gth + ((l * NB + ii) * 6 + j) * 3;
        float phi = p[0], tht = p[1], omg = p[2];
        float st, ct; __sincosf(0.5f * tht, &st, &ct);
        float sa, ca; __sincosf(-0.5f * (phi + omg), &sa, &ca);  // a = ca+i*sa
        float sb, cb; __sincosf(0.5f * (phi - omg), &sb, &cb);   // b = cb+i*sb
        rotS[idx] = make_float4(ca * ct, sa * ct, cb * st, sb * st);
    }
    __syncthreads();

    v2f res0 = {0.f, 0.f}, res1 = {0.f, 0.f}, res2 = {0.f, 0.f};
#pragma unroll
    for (int l = 0; l < NLAYER; ++l) {
        if (l) {
            // rewiring [3i-1, 3i+1, 3i+3] mod 96 within the 32-thread group
            int lm = (i + 31) & 31, lp = (i + 1) & 31;
            ang0 = (v2f){__shfl(res2.x, lm, 32), __shfl(res2.y, lm, 32)};
            ang1 = res1;
            ang2 = (v2f){__shfl(res0.x, lp, 32), __shfl(res0.y, lp, 32)};
        }
        float4 rr[6];
#pragma unroll
        for (int j = 0; j < 6; ++j) rr[j] = rotS[l * 192 + j * 32 + i];

        v2f c0, s0, c1, s1, c2v, s2v;
        sc2(ang0, s0, c0); sc2(ang1, s1, c1); sc2(ang2, s2v, c2v);

        // vl=0: Rot on each 1-qubit factor (real input), then tensor expand
        c2 A0, A1, B0, B1, C0, C1;
        apply1q(rr[0], c0, s0, A0, A1);
        apply1q(rr[1], c1, s1, B0, B1);
        apply1q(rr[2], c2v, s2v, C0, C1);
        c2 T00 = cmul2(A0, B0), T01 = cmul2(A0, B1);
        c2 T10 = cmul2(A1, B0), T11 = cmul2(A1, B1);
        c2 psi[8];
        psi[0] = cmul2(T00, C0); psi[1] = cmul2(T00, C1);
        psi[2] = cmul2(T01, C0); psi[3] = cmul2(T01, C1);
        psi[4] = cmul2(T10, C0); psi[5] = cmul2(T10, C1);
        psi[6] = cmul2(T11, C0); psi[7] = cmul2(T11, C1);

        // vl=0 CNOT ring, range 1: (0->1),(1->2),(2->0); wire bit: 4>>q
        cnot_c2(psi, 4, 2); cnot_c2(psi, 2, 1); cnot_c2(psi, 1, 4);

        // vl=1: full complex Rots
        gate_pk(psi, rr[3], 4); gate_pk(psi, rr[4], 2); gate_pk(psi, rr[5], 1);

        // vl=1 CNOT ring, range 2: (0->2),(1->0),(2->1)
        cnot_c2(psi, 4, 1); cnot_c2(psi, 2, 4); cnot_c2(psi, 1, 2);

        // measurement: Z on each wire
        v2f pb[8];
#pragma unroll
        for (int k = 0; k < 8; ++k)
            pb[k] = psi[k].re * psi[k].re + psi[k].im * psi[k].im;
        v2f s01 = pb[0] + pb[1], s23 = pb[2] + pb[3];
        v2f s45 = pb[4] + pb[5], s67 = pb[6] + pb[7];
        v2f q0 = pb[0] + pb[4], q1 = pb[1] + pb[5];
        v2f q2 = pb[2] + pb[6], q3 = pb[3] + pb[7];
        res0 = (s01 + s23) - (s45 + s67);
        res1 = (q0 + q1) - (q2 + q3);
        res2 = (q0 + q2) - (q1 + q3);
    }

    float* op0 = out + (size_t)bt0 * D_DIM + 3 * i;
    float* op1 = out + (size_t)bt1 * D_DIM + 3 * i;
    op0[0] = res0.x; op0[1] = res1.x; op0[2] = res2.x;
    op1[0] = res0.y; op1[1] = res1.y; op1[2] = res2.y;
}

extern "C" void kernel_launch(void* const* d_in, const int* in_sizes, int n_in,
                              void* d_out, int out_size, void* d_ws, size_t ws_size,
                              hipStream_t stream) {
    const float* x = (const float*)d_in[0];       // (128, 64, 96) f32
    const float* theta = (const float*)d_in[1];   // (64, 3, 32, 2, 3, 3) f32
    float* out = (float*)d_out;                   // (128, 64, 96) f32

    // grid: 64 t-values x 8 b-groups (16 b each, 2 per thread) = 512 blocks
    qnn_fused<<<64 * 8, 256, 0, stream>>>(x, theta, out);
}